// Round 14
// baseline (434.975 us; speedup 1.0000x reference)
//
#include <hip/hip_runtime.h>
#include <hip/hip_fp16.h>
#include <hip/hip_cooperative_groups.h>

namespace cg = cooperative_groups;

#define HID 128     // both IN_DIM and hidden dim are 128
#define NN 50000    // node count (fixed by the problem)
#define NW4 (NN / 4)  // u8-packed histogram words per row = 12500
#define NB 256      // grid blocks == hist edge-chunks (chunk = 3125)
#define CST 64      // padded CSR row stride (max in-degree ~45, Poisson(16))

typedef _Float16 f16;
typedef f16 f16x8 __attribute__((ext_vector_type(8)));
typedef float f32x4 __attribute__((ext_vector_type(4)));

// ---- e5m2 fp8 via byte-slicing of fp16 (decode = byte<<8, one v_perm) ----
__device__ __forceinline__ unsigned char enc8(float v) {
  __half h = __float2half(v);
  unsigned short b;
  __builtin_memcpy(&b, &h, 2);
  return (unsigned char)((b + 0x80u) >> 8);   // round-half-up into e5m2
}
__device__ __forceinline__ __half2 dec8h2(unsigned v) {  // 2 packed e5m2
  unsigned p = __builtin_amdgcn_perm(0u, v, 0x01040004u);
  __half2 h2;
  __builtin_memcpy(&h2, &p, 4);
  return h2;
}

struct Params {
  const float* attr; const int* src; const int* dst;
  const float* Ws; const float* bs; const float* decW; const float* decb;
  const float* token; const int* mask;
  unsigned char* X0; unsigned char* X1;
  f16* Wt; int* csr; unsigned char* rank;
  unsigned* pin; unsigned* pout;
  int* in_cnt; float* ns; float* nd; unsigned char* mmap;
  float* out;
  int N, E, NM, chunk;
  float scale;
};

// LDS plan (union via raw bytes):
//   P1 hist:   unsigned[NW4]                      = 50000 B
//   P2 merge:  tsum[8][128] + osum[8][128]        =  8192 B
//   P4-P6 gemm: Bs(34816) + Bs2(34816) + Yt(17408) + Xt(17408) = 104448 B
#define SH_BYTES 104448

// ---------------------------------------------------------------------------
// ONE cooperative kernel: R13's profile showed ~100 us of the 238 was
// inter-dispatch gaps (sum of kernels ~130 us). grid.sync() replaces the 9
// dispatch boundaries. 256 blocks x 1024 thr, 1 block/CU guaranteed
// (102 KB LDS, VGPR<=128 via launch_bounds). Layers fuse agg+GEMM the R9
// way but with the occupancy fixed: each wave aggregates only 4 nodes
// (16 waves share the 64-node tile), and all 16 waves split the GEMM
// (4 row-sets x 4 col-sets). A-operands come from LDS f16 -- the Y global
// round-trip is gone. Layer 2 chains W2 -> relu -> Xt(LDS) -> decW -> loss.
// ---------------------------------------------------------------------------
__global__ __launch_bounds__(1024, 4) void mega_kernel(Params p) {
  __shared__ char shraw[SH_BYTES] __attribute__((aligned(16)));
  cg::grid_group grid = cg::this_grid();
  const int b = blockIdx.x;
  const int t = threadIdx.x;
  const int wave = t >> 6, lane = t & 63;

  // ==== P1: per-block LDS histograms (R3: global atomics write through to
  // HBM at 32B/op; LDS atomics don't. ds_add_rtn byte = edge rank). ====
  {
    unsigned* hist = (unsigned*)shraw;
    if (b == 0 && t == 0) *p.out = 0.f;
    { int gi = b * 1024 + t; if (gi < NW4) ((unsigned*)p.mmap)[gi] = 0; }
    const int e0 = b * p.chunk, e1 = min(p.E, e0 + p.chunk);
    for (int i = t; i < NW4; i += 1024) hist[i] = 0;
    __syncthreads();
    for (int e = e0 + t; e < e1; e += 1024) {
      int d = p.dst[e];
      unsigned sh_ = 8u * (d & 3);
      unsigned old = atomicAdd(&hist[d >> 2], 1u << sh_);
      p.rank[e] = (unsigned char)((old >> sh_) & 0xffu);
    }
    __syncthreads();
    unsigned* rowI = p.pin + (size_t)b * NW4;
    for (int i = t; i < NW4; i += 1024) rowI[i] = hist[i];
    __syncthreads();
    for (int i = t; i < NW4; i += 1024) hist[i] = 0;
    __syncthreads();
    for (int e = e0 + t; e < e1; e += 1024) {
      int s = p.src[e];
      atomicAdd(&hist[s >> 2], 1u << (8u * (s & 3)));
    }
    __syncthreads();
    unsigned* rowO = p.pout + (size_t)b * NW4;
    for (int i = t; i < NW4; i += 1024) rowO[i] = hist[i];
  }
  grid.sync();

  // ==== P2: merge -- exclusive prefix over the 256 hist blocks, u8x4
  // packed (degrees << 256: no cross-byte carry). 128 words x 8 tiles. ====
  {
    unsigned (*tsum)[128] = (unsigned(*)[128])shraw;
    unsigned (*osum)[128] = (unsigned(*)[128])(shraw + 4096);
    { int gi = b * 1024 + t; if (gi < p.NM) p.mmap[p.mask[gi]] = 1; }
    const int wl = t & 127, tile = t >> 7;
    for (int vb = b; vb < (NW4 + 127) / 128; vb += NB) {
      int w = vb * 128 + wl;
      bool ok = w < NW4;
      unsigned v[32];
      unsigned s = 0, so = 0;
      if (ok) {
#pragma unroll
        for (int j = 0; j < 32; ++j)
          v[j] = p.pin[(size_t)(tile * 32 + j) * NW4 + w];
#pragma unroll
        for (int j = 0; j < 32; ++j) {
          unsigned x = v[j];
          v[j] = s;
          s += x;
        }
#pragma unroll
        for (int j = 0; j < 32; ++j)
          so += p.pout[(size_t)(tile * 32 + j) * NW4 + w];
      }
      tsum[tile][wl] = s;
      osum[tile][wl] = so;
      __syncthreads();
      unsigned toff = 0;
      for (int k = 0; k < tile; ++k) toff += tsum[k][wl];
      if (ok) {
#pragma unroll
        for (int j = 0; j < 32; ++j)
          p.pin[(size_t)(tile * 32 + j) * NW4 + w] = v[j] + toff;
        if (tile == 7) {
          unsigned tin = toff + s, tout = 0;
#pragma unroll
          for (int k = 0; k < 8; ++k) tout += osum[k][wl];
          int i0 = tin & 0xffu, i1 = (tin >> 8) & 0xffu,
              i2 = (tin >> 16) & 0xffu, i3 = (tin >> 24) & 0xffu;
          int o0 = tout & 0xffu, o1 = (tout >> 8) & 0xffu,
              o2 = (tout >> 16) & 0xffu, o3 = (tout >> 24) & 0xffu;
          ((int4*)p.in_cnt)[w] = make_int4(i0, i1, i2, i3);
          ((float4*)p.nd)[w] = make_float4(rsqrtf((float)max(i0, 1)),
                                           rsqrtf((float)max(i1, 1)),
                                           rsqrtf((float)max(i2, 1)),
                                           rsqrtf((float)max(i3, 1)));
          ((float4*)p.ns)[w] = make_float4(rsqrtf((float)max(o0, 1)),
                                           rsqrtf((float)max(o1, 1)),
                                           rsqrtf((float)max(o2, 1)),
                                           rsqrtf((float)max(o3, 1)));
        }
      }
      __syncthreads();
    }
  }
  grid.sync();

  // ==== P3: fill (atomic-free, padded CSR) + weight transpose + X0 prep
  // (mask folded via bytemap; ns prescaled into X0). ====
  {
    const int e0 = b * p.chunk, e1 = min(p.E, e0 + p.chunk);
    const unsigned* row = p.pin + (size_t)b * NW4;
    for (int e = e0 + t; e < e1; e += 1024) {
      int s = p.src[e], d = p.dst[e];
      unsigned base = (row[d >> 2] >> (8u * (d & 3))) & 0xffu;
      p.csr[d * CST + (int)base + (int)p.rank[e]] = s;
    }
    for (int i = b * 1024 + t; i < 4 * 16384; i += NB * 1024) {
      int m = i >> 14, rem = i & 16383, n = rem >> 7, k = rem & 127;
      const float* Wsrc = (m < 3) ? (p.Ws + (size_t)m * 16384) : p.decW;
      p.Wt[i] = (f16)Wsrc[k * 128 + n];
    }
    int n4 = p.N * 32;
    for (int i = b * 1024 + t; i < n4; i += NB * 1024) {
      int r = i >> 5, c4 = i & 31;
      float s = p.ns[r];
      float4 v = p.mmap[r] ? ((const float4*)p.token)[c4]
                           : ((const float4*)p.attr)[i];
      ((uchar4*)p.X0)[i] = make_uchar4(enc8(s * v.x), enc8(s * v.y),
                                       enc8(s * v.z), enc8(s * v.w));
    }
  }
  grid.sync();

  f16* Bs  = (f16*)shraw;
  f16* Bs2 = (f16*)(shraw + 34816);
  f16* Yt  = (f16*)(shraw + 2 * 34816);
  f16* Xt  = (f16*)(shraw + 2 * 34816 + 17408);
  const int ln = lane & 15, kq = lane >> 4;

  // ==== P4/P5: layers 0,1 (full graph). Wave w aggregates 4 nodes into Yt
  // rows w*4..+3 (R13 perm+pk_add inner loop); 16 waves then split the GEMM
  // (wave: rows (w&3)*16, ntiles (w>>2)*2). Epilogue: relu(+b)*ns -> fp8. ====
  const unsigned char* Xi = p.X0;
  unsigned char* Xo = p.X1;
  for (int l = 0; l < 2; ++l) {
    const f16* W = p.Wt + (size_t)l * 16384;
    for (int i = t; i < 2048; i += 1024) {
      int n = i >> 4, c = i & 15;
      *(f16x8*)&Bs[n * 136 + c * 8] = *(const f16x8*)&W[n * 128 + c * 8];
    }
    const unsigned short* Xs = (const unsigned short*)Xi;
    const int nvb = (p.N + 63) / 64;
    for (int vb = b; vb < nvb; vb += NB) {
      for (int i = 0; i < 4; ++i) {
        int nl = wave * 4 + i;
        int node = vb * 64 + nl;
        bool ok = node < p.N;
        int safe = ok ? node : 0;
        int cnt = ok ? p.in_cnt[safe] : 0;
        int idx = p.csr[safe * CST + lane];
        __half2 z = __floats2half2_rn(0.f, 0.f);
        __half2 a0 = z, a1 = z, a2 = z, a3 = z;
        int j = 0;
        for (; j + 4 <= cnt; j += 4) {
          int s0 = __shfl(idx, j + 0);
          int s1 = __shfl(idx, j + 1);
          int s2 = __shfl(idx, j + 2);
          int s3 = __shfl(idx, j + 3);
          a0 = __hadd2(a0, dec8h2(Xs[(size_t)s0 * 64 + lane]));
          a1 = __hadd2(a1, dec8h2(Xs[(size_t)s1 * 64 + lane]));
          a2 = __hadd2(a2, dec8h2(Xs[(size_t)s2 * 64 + lane]));
          a3 = __hadd2(a3, dec8h2(Xs[(size_t)s3 * 64 + lane]));
        }
        for (; j < cnt; ++j) {
          int s0 = __shfl(idx, j);
          a0 = __hadd2(a0, dec8h2(Xs[(size_t)s0 * 64 + lane]));
        }
        __half2 hs = __hadd2(__hadd2(a0, a1), __hadd2(a2, a3));
        float2 f = __half22float2(hs);
        float ndv = p.nd[safe];
        *(__half2*)&Yt[nl * 136 + lane * 2] = __floats2half2_rn(f.x * ndv, f.y * ndv);
      }
      __syncthreads();                 // Yt complete (+ Bs staged, first iter)
      const int r0 = (wave & 3) * 16;
      const int nb0 = (wave >> 2) * 2;
      f16x8 af[4];
#pragma unroll
      for (int ki = 0; ki < 4; ++ki)
        af[ki] = *(const f16x8*)&Yt[(r0 + ln) * 136 + ki * 32 + kq * 8];
      f32x4 acc[2] = {{0.f, 0.f, 0.f, 0.f}, {0.f, 0.f, 0.f, 0.f}};
#pragma unroll
      for (int ki = 0; ki < 4; ++ki)
#pragma unroll
        for (int nt = 0; nt < 2; ++nt) {
          f16x8 bf = *(const f16x8*)&Bs[((nb0 + nt) * 16 + ln) * 136 + ki * 32 + kq * 8];
          acc[nt] = __builtin_amdgcn_mfma_f32_16x16x32_f16(af[ki], bf, acc[nt], 0, 0, 0);
        }
      const int orow = vb * 64 + r0 + kq * 4;
      float rs[4];
#pragma unroll
      for (int r = 0; r < 4; ++r)
        rs[r] = (orow + r < p.N) ? p.ns[orow + r] : 1.f;   // prescale (l<2)
#pragma unroll
      for (int nt = 0; nt < 2; ++nt) {
        int col = (nb0 + nt) * 16 + ln;
        float bb = p.bs[l * 128 + col];
#pragma unroll
        for (int r = 0; r < 4; ++r) {
          int gr = orow + r;
          if (gr < p.N)
            Xo[(size_t)gr * HID + col] = enc8(fmaxf(acc[nt][r] + bb, 0.f) * rs[r]);
        }
      }
      __syncthreads();                 // Yt reuse next vb
    }
    grid.sync();
    const unsigned char* tmp = Xi;
    Xi = Xo;
    Xo = (unsigned char*)tmp;
  }

  // ==== P6: layer 2 (masked nodes only) + decoder + loss, all in LDS. ====
  {
    const f16* W2 = p.Wt + (size_t)2 * 16384;
    const f16* Wd = p.Wt + (size_t)3 * 16384;
    for (int i = t; i < 2048; i += 1024) {
      int n = i >> 4, c = i & 15;
      *(f16x8*)&Bs[n * 136 + c * 8]  = *(const f16x8*)&W2[n * 128 + c * 8];
      *(f16x8*)&Bs2[n * 136 + c * 8] = *(const f16x8*)&Wd[n * 128 + c * 8];
    }
    const unsigned short* Xs = (const unsigned short*)Xi;
    float part = 0.f;
    const int nvb = (p.NM + 63) / 64;
    for (int vb = b; vb < nvb; vb += NB) {
      for (int i = 0; i < 4; ++i) {
        int nl = wave * 4 + i;
        int gi = vb * 64 + nl;
        bool ok = gi < p.NM;
        int node = ok ? p.mask[gi] : 0;
        int cnt = ok ? p.in_cnt[node] : 0;
        int idx = p.csr[node * CST + lane];
        __half2 z = __floats2half2_rn(0.f, 0.f);
        __half2 a0 = z, a1 = z, a2 = z, a3 = z;
        int j = 0;
        for (; j + 4 <= cnt; j += 4) {
          int s0 = __shfl(idx, j + 0);
          int s1 = __shfl(idx, j + 1);
          int s2 = __shfl(idx, j + 2);
          int s3 = __shfl(idx, j + 3);
          a0 = __hadd2(a0, dec8h2(Xs[(size_t)s0 * 64 + lane]));
          a1 = __hadd2(a1, dec8h2(Xs[(size_t)s1 * 64 + lane]));
          a2 = __hadd2(a2, dec8h2(Xs[(size_t)s2 * 64 + lane]));
          a3 = __hadd2(a3, dec8h2(Xs[(size_t)s3 * 64 + lane]));
        }
        for (; j < cnt; ++j) {
          int s0 = __shfl(idx, j);
          a0 = __hadd2(a0, dec8h2(Xs[(size_t)s0 * 64 + lane]));
        }
        __half2 hs = __hadd2(__hadd2(a0, a1), __hadd2(a2, a3));
        float2 f = __half22float2(hs);
        float ndv = p.nd[node];
        *(__half2*)&Yt[nl * 136 + lane * 2] =
            __floats2half2_rn(ok ? f.x * ndv : 0.f, ok ? f.y * ndv : 0.f);
      }
      __syncthreads();
      const int r0 = (wave & 3) * 16;
      const int nb0 = (wave >> 2) * 2;
      f16x8 af[4];
#pragma unroll
      for (int ki = 0; ki < 4; ++ki)
        af[ki] = *(const f16x8*)&Yt[(r0 + ln) * 136 + ki * 32 + kq * 8];
      f32x4 acc[2] = {{0.f, 0.f, 0.f, 0.f}, {0.f, 0.f, 0.f, 0.f}};
#pragma unroll
      for (int ki = 0; ki < 4; ++ki)
#pragma unroll
        for (int nt = 0; nt < 2; ++nt) {
          f16x8 bf = *(const f16x8*)&Bs[((nb0 + nt) * 16 + ln) * 136 + ki * 32 + kq * 8];
          acc[nt] = __builtin_amdgcn_mfma_f32_16x16x32_f16(af[ki], bf, acc[nt], 0, 0, 0);
        }
      const int lrow = r0 + kq * 4;
#pragma unroll
      for (int nt = 0; nt < 2; ++nt) {
        int col = (nb0 + nt) * 16 + ln;
        float bb = p.bs[2 * 128 + col];
#pragma unroll
        for (int r = 0; r < 4; ++r)
          Xt[(lrow + r) * 136 + col] = (f16)fmaxf(acc[nt][r] + bb, 0.f);
      }
      __syncthreads();
      f16x8 ag[4];
#pragma unroll
      for (int ki = 0; ki < 4; ++ki)
        ag[ki] = *(const f16x8*)&Xt[(r0 + ln) * 136 + ki * 32 + kq * 8];
      f32x4 ac2[2] = {{0.f, 0.f, 0.f, 0.f}, {0.f, 0.f, 0.f, 0.f}};
#pragma unroll
      for (int ki = 0; ki < 4; ++ki)
#pragma unroll
        for (int nt = 0; nt < 2; ++nt) {
          f16x8 bf = *(const f16x8*)&Bs2[((nb0 + nt) * 16 + ln) * 136 + ki * 32 + kq * 8];
          ac2[nt] = __builtin_amdgcn_mfma_f32_16x16x32_f16(ag[ki], bf, ac2[nt], 0, 0, 0);
        }
      const int orow = vb * 64 + r0 + kq * 4;
      int mrow[4];
#pragma unroll
      for (int r = 0; r < 4; ++r)
        mrow[r] = (orow + r < p.NM) ? p.mask[orow + r] : -1;
#pragma unroll
      for (int nt = 0; nt < 2; ++nt) {
        int col = (nb0 + nt) * 16 + ln;
        float db = p.decb[col];
#pragma unroll
        for (int r = 0; r < 4; ++r) {
          if (mrow[r] >= 0) {
            float d = ac2[nt][r] + db - p.attr[(size_t)mrow[r] * HID + col];
            part += d * d;
          }
        }
      }
      __syncthreads();                 // Yt/Xt reuse next vb
    }
    // block reduction: wave shfl -> 16-entry LDS -> one atomic per block
#pragma unroll
    for (int off = 32; off > 0; off >>= 1) part += __shfl_down(part, off);
    float* wsum = (float*)Yt;
    __syncthreads();
    if (lane == 0) wsum[wave] = part;
    __syncthreads();
    if (t == 0) {
      float s = 0.f;
      for (int k = 0; k < 16; ++k) s += wsum[k];
      atomicAdd(p.out, s * p.scale);
    }
  }
}

// ---------------------------------------------------------------------------
extern "C" void kernel_launch(void* const* d_in, const int* in_sizes, int n_in,
                              void* d_out, int out_size, void* d_ws, size_t ws_size,
                              hipStream_t stream) {
  Params p;
  p.attr  = (const float*)d_in[0];
  p.src   = (const int*)d_in[1];
  p.dst   = (const int*)d_in[2];
  p.Ws    = (const float*)d_in[3];
  p.bs    = (const float*)d_in[4];
  p.decW  = (const float*)d_in[5];
  p.decb  = (const float*)d_in[6];
  p.token = (const float*)d_in[7];
  p.mask  = (const int*)d_in[8];
  p.N  = in_sizes[0] / HID;          // 50000
  p.E  = in_sizes[1];                // 800000
  p.NM = in_sizes[8];                // 15000
  p.chunk = (p.E + NB - 1) / NB;     // 3125
  p.scale = 1.f / ((float)p.NM * HID);
  p.out = (float*)d_out;

  // Workspace layout (16B-aligned pieces; total ~52.5 MB)
  char* w = (char*)d_ws;
  p.X0 = (unsigned char*)w;  w += (size_t)p.N * HID;
  p.X1 = (unsigned char*)w;  w += (size_t)p.N * HID;
  p.Wt = (f16*)w;            w += (size_t)4 * HID * HID * 2;
  p.csr = (int*)w;           w += (size_t)NN * CST * 4;
  p.rank = (unsigned char*)w; w += (size_t)p.E;
  p.pin = (unsigned*)w;      w += (size_t)NB * NW4 * 4;
  p.pout = (unsigned*)w;     w += (size_t)NB * NW4 * 4;
  p.in_cnt = (int*)w;        w += (size_t)p.N * 4;
  p.ns = (float*)w;          w += (size_t)p.N * 4;
  p.nd = (float*)w;          w += (size_t)p.N * 4;
  p.mmap = (unsigned char*)w; w += (size_t)NW4 * 4;

  void* args[] = {&p};
  hipLaunchCooperativeKernel((const void*)mega_kernel, dim3(NB), dim3(1024),
                             args, 0, stream);
}

// Round 15
// 240.464 us; speedup vs baseline: 1.8089x; 1.8089x over previous
//
#include <hip/hip_runtime.h>
#include <hip/hip_fp16.h>

#define HID 128     // both IN_DIM and hidden dim are 128
#define NN 50000    // node count (fixed by the problem)
#define NW4 (NN / 4)  // u8-packed histogram words per row = 12500
#define NB 256      // edge-chunk blocks: chunk = 3125 -> per-(block,node) count << 256
#define CST 64      // padded CSR row stride (max in-degree ~45 for Poisson(16))

typedef _Float16 f16;
typedef f16 f16x8 __attribute__((ext_vector_type(8)));
typedef float f32x4 __attribute__((ext_vector_type(4)));

// ---- e5m2 fp8 via byte-slicing of fp16 ------------------------------------
// e5m2 is exactly the high byte of fp16: decode = byte<<8 (one v_perm_b32),
// encode = round-half-up on the low byte.
__device__ __forceinline__ unsigned char enc8(float v) {
  __half h = __float2half(v);
  unsigned short b;
  __builtin_memcpy(&b, &h, 2);
  return (unsigned char)((b + 0x80u) >> 8);
}
// 2 packed e5m2 (ushort) -> half2 in ONE v_perm_b32: bytes [0,b0,0,b1]
__device__ __forceinline__ __half2 dec8h2(unsigned v) {
  unsigned p = __builtin_amdgcn_perm(0u, v, 0x01040004u);
  __half2 h2;
  __builtin_memcpy(&h2, &p, 4);
  return h2;
}
__device__ __forceinline__ f16x8 dec8x8(const unsigned char* p) {  // 8 packed e5m2
  uint2 u = *(const uint2*)p;
  unsigned r[4];
  r[0] = __builtin_amdgcn_perm(0u, u.x, 0x01040004u);   // [0,b0,0,b1]
  r[1] = __builtin_amdgcn_perm(0u, u.x, 0x03040204u);   // [0,b2,0,b3]
  r[2] = __builtin_amdgcn_perm(0u, u.y, 0x01040004u);
  r[3] = __builtin_amdgcn_perm(0u, u.y, 0x03040204u);
  f16x8 out;
  __builtin_memcpy(&out, r, 16);
  return out;
}

// ---------------------------------------------------------------------------
// CSR build phase 1: per-block PRIVATE LDS histograms, u8 x4 packed.
// (R3: global atomics write through to HBM at 32B/op regardless of scope;
// LDS atomics don't. ds_add_rtn byte = edge rank.) Also zeroes d_out and
// the masked-node bytemap (set by merge, read by fillprep).
// ---------------------------------------------------------------------------
__global__ __launch_bounds__(256) void hist_kernel(
    const int* __restrict__ src, const int* __restrict__ dst,
    unsigned* __restrict__ pin, unsigned* __restrict__ pout,
    unsigned char* __restrict__ rank, float* __restrict__ d_out_f,
    unsigned* __restrict__ mmap_w, int E, int chunk) {
  __shared__ unsigned hist[NW4];    // 50 KB -> 3 blocks/CU
  const int b = blockIdx.x;
  const int e0 = b * chunk, e1 = min(E, e0 + chunk);
  if (b == 0 && threadIdx.x == 0) *d_out_f = 0.f;
  if (b < 49) {                     // zero 50000-byte bytemap as words
    int wi = b * 256 + threadIdx.x;
    if (wi < NW4) mmap_w[wi] = 0;
  }

  for (int i = threadIdx.x; i < NW4; i += 256) hist[i] = 0;
  __syncthreads();
  for (int e = e0 + threadIdx.x; e < e1; e += 256) {
    int d = dst[e];
    unsigned sh = 8u * (d & 3);
    unsigned old = atomicAdd(&hist[d >> 2], 1u << sh);   // LDS atomic
    rank[e] = (unsigned char)((old >> sh) & 0xffu);
  }
  __syncthreads();
  unsigned* rowI = pin + (size_t)b * NW4;
  for (int i = threadIdx.x; i < NW4; i += 256) rowI[i] = hist[i];
  __syncthreads();                  // row dump done before re-zero
  for (int i = threadIdx.x; i < NW4; i += 256) hist[i] = 0;
  __syncthreads();
  for (int e = e0 + threadIdx.x; e < e1; e += 256) {
    int s = src[e];
    atomicAdd(&hist[s >> 2], 1u << (8u * (s & 3)));
  }
  __syncthreads();
  unsigned* rowO = pout + (size_t)b * NW4;
  for (int i = threadIdx.x; i < NW4; i += 256) rowO[i] = hist[i];
}

// ---------------------------------------------------------------------------
// CSR build phase 2: scan over the 256 hist blocks, parallel in both axes
// (R4: serial-b version was latency-starved at 1.9% occupancy). Block =
// 32 words x 8 tiles; per-thread 32 b's in registers, in-register exclusive
// prefix, 8-tile LDS scan. u8x4-packed arithmetic (degrees << 256: no carry).
// Also sets the masked-node bytemap (zeroed by hist).
// ---------------------------------------------------------------------------
__global__ __launch_bounds__(256) void merge_kernel(
    unsigned* __restrict__ pin, const unsigned* __restrict__ pout,
    int* __restrict__ in_cnt, float* __restrict__ ns, float* __restrict__ nd,
    const int* __restrict__ mask, unsigned char* __restrict__ mmap, int nm) {
  int gi = blockIdx.x * 256 + threadIdx.x;
  if (gi < nm) mmap[mask[gi]] = 1;   // 391*256 threads >= 15000

  __shared__ unsigned tsum[8][32];
  __shared__ unsigned osum[8][32];
  const int wl = threadIdx.x & 31;   // word slot within block
  const int tile = threadIdx.x >> 5; // 0..7 -> b's [tile*32, tile*32+32)
  const int w = blockIdx.x * 32 + wl;
  const bool ok = w < NW4;

  unsigned v[32];
  unsigned s = 0, so = 0;
  if (ok) {
#pragma unroll
    for (int j = 0; j < 32; ++j)
      v[j] = pin[(size_t)(tile * 32 + j) * NW4 + w];
#pragma unroll
    for (int j = 0; j < 32; ++j) {  // in-register exclusive prefix (packed)
      unsigned x = v[j];
      v[j] = s;
      s += x;
    }
#pragma unroll
    for (int j = 0; j < 32; ++j)
      so += pout[(size_t)(tile * 32 + j) * NW4 + w];
  }
  tsum[tile][wl] = s;
  osum[tile][wl] = so;
  __syncthreads();
  unsigned toff = 0;
  for (int k = 0; k < tile; ++k) toff += tsum[k][wl];
  if (ok) {
#pragma unroll
    for (int j = 0; j < 32; ++j)
      pin[(size_t)(tile * 32 + j) * NW4 + w] = v[j] + toff;
    if (tile == 7) {
      unsigned tin = toff + s;      // packed in-degrees of the 4 nodes
      unsigned tout = 0;
#pragma unroll
      for (int k = 0; k < 8; ++k) tout += osum[k][wl];
      int i0 = tin & 0xffu, i1 = (tin >> 8) & 0xffu,
          i2 = (tin >> 16) & 0xffu, i3 = (tin >> 24) & 0xffu;
      int o0 = tout & 0xffu, o1 = (tout >> 8) & 0xffu,
          o2 = (tout >> 16) & 0xffu, o3 = (tout >> 24) & 0xffu;
      ((int4*)in_cnt)[w] = make_int4(i0, i1, i2, i3);
      ((float4*)nd)[w] = make_float4(rsqrtf((float)max(i0, 1)),
                                     rsqrtf((float)max(i1, 1)),
                                     rsqrtf((float)max(i2, 1)),
                                     rsqrtf((float)max(i3, 1)));
      ((float4*)ns)[w] = make_float4(rsqrtf((float)max(o0, 1)),
                                     rsqrtf((float)max(o1, 1)),
                                     rsqrtf((float)max(o2, 1)),
                                     rsqrtf((float)max(o3, 1)));
    }
  }
}

// ---------------------------------------------------------------------------
// Fused phase 3 (everything that depends only on merge, disjoint outputs):
//   blocks [0,256):    atomic-free CSR fill (padded, stride 64/node)
//   blocks [256,512):  weight transpose -> fp16 Wt[m][n][k]
//   blocks [512,...):  X0 = enc8(ns[row] * (masked ? token : attr[row]))
//                      (mask folded in via bytemap -- mask_h dispatch gone)
// ---------------------------------------------------------------------------
__global__ __launch_bounds__(256) void fillprep_kernel(
    const int* __restrict__ src, const int* __restrict__ dst,
    const unsigned char* __restrict__ rank, const unsigned* __restrict__ pin,
    int* __restrict__ csr,
    const float* __restrict__ attr, const float* __restrict__ Ws,
    const float* __restrict__ decW, const float* __restrict__ ns,
    const float* __restrict__ token, const unsigned char* __restrict__ mmap,
    unsigned char* __restrict__ X, f16* __restrict__ Wt,
    int E, int chunk, int n4) {
  const int b = blockIdx.x;
  if (b < 256) {
    const int e0 = b * chunk, e1 = min(E, e0 + chunk);
    const unsigned* __restrict__ row = pin + (size_t)b * NW4;
    for (int e = e0 + threadIdx.x; e < e1; e += 256) {
      int s = src[e], d = dst[e];
      unsigned base = (row[d >> 2] >> (8u * (d & 3))) & 0xffu;
      csr[d * CST + (int)base + (int)rank[e]] = s;
    }
  } else if (b < 512) {
    int i = (b - 256) * 256 + threadIdx.x;    // exactly 4*128*128
    int m = i >> 14, rem = i & 16383, n = rem >> 7, k = rem & 127;
    const float* Wsrc = (m < 3) ? (Ws + (size_t)m * 16384) : decW;
    Wt[i] = (f16)Wsrc[k * 128 + n];
  } else {
    int i = (b - 512) * 256 + threadIdx.x;
    if (i < n4) {
      int r = i >> 5, c4 = i & 31;
      float s = ns[r];
      float4 v = mmap[r] ? ((const float4*)token)[c4] : ((const float4*)attr)[i];
      ((uchar4*)X)[i] = make_uchar4(enc8(s * v.x), enc8(s * v.y),
                                    enc8(s * v.z), enc8(s * v.w));
    }
  }
}

// ---------------------------------------------------------------------------
// CSR aggregation (one wave per node -- R9/R14 both proved this parallelism
// is the resource; fusing agg into GEMM phases loses every time). Whole
// padded csr row in ONE coalesced 64-lane load; __shfl feeds edge indices
// with zero memory latency; v_perm decode + v_pk_add_f16 accumulation
// (~4 instr/edge). fp16 accum noise (~0.3%) << e5m2 quantization (12%).
// glist != null: process only nodes glist[0..n), writing Y compactly.
// ---------------------------------------------------------------------------
__global__ __launch_bounds__(256) void agg_kernel(
    const unsigned short* __restrict__ X, const int* __restrict__ csr,
    const int* __restrict__ in_cnt, const float* __restrict__ nd,
    const int* __restrict__ glist, unsigned short* __restrict__ Y, int n) {
  int ni = (blockIdx.x * blockDim.x + threadIdx.x) >> 6;
  int lane = threadIdx.x & 63;
  if (ni >= n) return;
  int node = glist ? glist[ni] : ni;
  int cnt = in_cnt[node];
  int idx = csr[node * CST + lane];   // whole padded row, one load
  __half2 z = __floats2half2_rn(0.f, 0.f);
  __half2 a0 = z, a1 = z, a2 = z, a3 = z;
  int i = 0;
  for (; i + 4 <= cnt; i += 4) {
    int s0 = __shfl(idx, i + 0);
    int s1 = __shfl(idx, i + 1);
    int s2 = __shfl(idx, i + 2);
    int s3 = __shfl(idx, i + 3);
    __half2 v0 = dec8h2(X[(size_t)s0 * 64 + lane]);
    __half2 v1 = dec8h2(X[(size_t)s1 * 64 + lane]);
    __half2 v2 = dec8h2(X[(size_t)s2 * 64 + lane]);
    __half2 v3 = dec8h2(X[(size_t)s3 * 64 + lane]);
    a0 = __hadd2(a0, v0);
    a1 = __hadd2(a1, v1);
    a2 = __hadd2(a2, v2);
    a3 = __hadd2(a3, v3);
  }
  for (; i < cnt; ++i) {
    int s = __shfl(idx, i);
    a0 = __hadd2(a0, dec8h2(X[(size_t)s * 64 + lane]));
  }
  __half2 hs = __hadd2(__hadd2(a0, a1), __hadd2(a2, a3));
  float2 f = __half22float2(hs);
  float ndv = nd[node];
  unsigned char lo = enc8(f.x * ndv), hi = enc8(f.y * ndv);
  Y[(size_t)ni * 64 + lane] = (unsigned short)(lo | (hi << 8));
}

// ---------------------------------------------------------------------------
// MFMA fp16 GEMM (layers, 64 rows/block keeps grid > CU count -- R11's
// 128-row variant idled 60 CUs): X' = relu(Y @ W + b)[, * ns] -> fp8.
// A (Y) fp8-e5m2 decoded via v_perm to f16. B-tile LDS stride 136 halves
// (2-way = free). Layouts (HW-verified): A[m=lane&15][k=(lane>>4)*8+j];
// C/D col=lane&15, row=(lane>>4)*4+reg.
// ---------------------------------------------------------------------------
__global__ __launch_bounds__(256) void gemm_layer_kernel(
    const unsigned char* __restrict__ A8, const f16* __restrict__ Wt,
    unsigned char* __restrict__ out, const float* __restrict__ col_bias,
    const float* __restrict__ row_scale, int M) {
  __shared__ f16 Bs[128 * 136];     // 34.8 KB
  const int t = threadIdx.x;
  for (int i = t; i < 2048; i += 256) {
    int n = i >> 4, c = i & 15;
    *(f16x8*)&Bs[n * 136 + c * 8] = *(const f16x8*)&Wt[n * 128 + c * 8];
  }
  const int wave = t >> 6, lane = t & 63;
  const int ln = lane & 15, kq = lane >> 4;
  const int mBase = blockIdx.x * 64 + wave * 16;

  const int am = mBase + ln;
  const int rowA = (am < M) ? am : 0;
  const unsigned char* Ap = A8 + (size_t)rowA * HID + kq * 8;
  f16x8 af[4];
#pragma unroll
  for (int ki = 0; ki < 4; ++ki) af[ki] = dec8x8(Ap + ki * 32);

  f32x4 acc[8];
#pragma unroll
  for (int nt = 0; nt < 8; ++nt) acc[nt] = (f32x4){0.f, 0.f, 0.f, 0.f};
  __syncthreads();
#pragma unroll
  for (int ki = 0; ki < 4; ++ki) {
#pragma unroll
    for (int nt = 0; nt < 8; ++nt) {
      f16x8 bf = *(const f16x8*)&Bs[(nt * 16 + ln) * 136 + ki * 32 + kq * 8];
      acc[nt] = __builtin_amdgcn_mfma_f32_16x16x32_f16(af[ki], bf, acc[nt], 0, 0, 0);
    }
  }
  const int orow = mBase + kq * 4;
  float rs[4];
#pragma unroll
  for (int r = 0; r < 4; ++r)
    rs[r] = (row_scale && orow + r < M) ? row_scale[orow + r] : 1.f;
#pragma unroll
  for (int nt = 0; nt < 8; ++nt) {
    int col = nt * 16 + ln;
    float bb = col_bias[col];
#pragma unroll
    for (int r = 0; r < 4; ++r) {
      int gr = orow + r;
      if (gr < M) {
        float v = fmaxf(acc[nt][r] + bb, 0.f) * rs[r];
        out[(size_t)gr * HID + col] = enc8(v);
      }
    }
  }
}

// ---------------------------------------------------------------------------
// Decoder GEMM with FUSED loss: A rows are COMPACT (row i = masked node
// mask[i]'s features, produced by the masked-only layer 2); mask is used
// only to index attr for the compare. recon never hits memory.
// ---------------------------------------------------------------------------
__global__ __launch_bounds__(256) void gemm_loss_kernel(
    const unsigned char* __restrict__ A8, const f16* __restrict__ Wt,
    const float* __restrict__ col_bias, const int* __restrict__ mask,
    const float* __restrict__ attr, float* __restrict__ out, int M, float scale) {
  __shared__ f16 Bs[128 * 136];
  const int t = threadIdx.x;
  for (int i = t; i < 2048; i += 256) {
    int n = i >> 4, c = i & 15;
    *(f16x8*)&Bs[n * 136 + c * 8] = *(const f16x8*)&Wt[n * 128 + c * 8];
  }
  const int wave = t >> 6, lane = t & 63;
  const int ln = lane & 15, kq = lane >> 4;
  const int mBase = blockIdx.x * 64 + wave * 16;

  const int am = mBase + ln;
  const int rowA = (am < M) ? am : 0;            // compact rows
  const unsigned char* Ap = A8 + (size_t)rowA * HID + kq * 8;
  f16x8 af[4];
#pragma unroll
  for (int ki = 0; ki < 4; ++ki) af[ki] = dec8x8(Ap + ki * 32);

  f32x4 acc[8];
#pragma unroll
  for (int nt = 0; nt < 8; ++nt) acc[nt] = (f32x4){0.f, 0.f, 0.f, 0.f};
  __syncthreads();
#pragma unroll
  for (int ki = 0; ki < 4; ++ki) {
#pragma unroll
    for (int nt = 0; nt < 8; ++nt) {
      f16x8 bf = *(const f16x8*)&Bs[(nt * 16 + ln) * 136 + ki * 32 + kq * 8];
      acc[nt] = __builtin_amdgcn_mfma_f32_16x16x32_f16(af[ki], bf, acc[nt], 0, 0, 0);
    }
  }
  const int orow = mBase + kq * 4;
  int mrow[4];
#pragma unroll
  for (int r = 0; r < 4; ++r) mrow[r] = (orow + r < M) ? mask[orow + r] : -1;
  float part = 0.f;
#pragma unroll
  for (int nt = 0; nt < 8; ++nt) {
    int col = nt * 16 + ln;
    float bb = col_bias[col];
#pragma unroll
    for (int r = 0; r < 4; ++r) {
      if (mrow[r] >= 0) {
        float d = acc[nt][r] + bb - attr[(size_t)mrow[r] * HID + col];
        part += d * d;
      }
    }
  }
#pragma unroll
  for (int off = 32; off > 0; off >>= 1) part += __shfl_down(part, off);
  __shared__ float wsum[4];
  if (lane == 0) wsum[wave] = part;
  __syncthreads();
  if (t == 0)
    atomicAdd(out, (wsum[0] + wsum[1] + wsum[2] + wsum[3]) * scale);
}

// ---------------------------------------------------------------------------
extern "C" void kernel_launch(void* const* d_in, const int* in_sizes, int n_in,
                              void* d_out, int out_size, void* d_ws, size_t ws_size,
                              hipStream_t stream) {
  const float* attr  = (const float*)d_in[0];
  const int*   src   = (const int*)d_in[1];
  const int*   dst   = (const int*)d_in[2];
  const float* Ws    = (const float*)d_in[3];
  const float* bs    = (const float*)d_in[4];
  const float* decW  = (const float*)d_in[5];
  const float* decb  = (const float*)d_in[6];
  const float* token = (const float*)d_in[7];
  const int*   mask  = (const int*)d_in[8];

  const int N  = in_sizes[0] / HID;   // 50000
  const int E  = in_sizes[1];         // 800000
  const int NM = in_sizes[8];         // 15000
  const int chunk = (E + NB - 1) / NB;  // 3125

  // Workspace layout (16B-aligned pieces; total ~53 MB)
  char* w = (char*)d_ws;
  unsigned char* X = (unsigned char*)w;  w += (size_t)N * HID;  // fp8 features
  unsigned char* Y = (unsigned char*)w;  w += (size_t)N * HID;  // fp8 agg out
  f16* Wt = (f16*)w;           w += (size_t)4 * HID * HID * 2;
  int* csr = (int*)w;          w += (size_t)NN * CST * 4;       // padded CSR
  unsigned char* rank = (unsigned char*)w;  w += (size_t)E;
  unsigned* pin = (unsigned*)w;  w += (size_t)NB * NW4 * 4;
  unsigned* pout = (unsigned*)w; w += (size_t)NB * NW4 * 4;
  int* in_cnt = (int*)w;       w += (size_t)N * 4;
  float* ns = (float*)w;       w += (size_t)N * 4;
  float* nd = (float*)w;       w += (size_t)N * 4;
  unsigned char* mmap = (unsigned char*)w;  w += (size_t)NW4 * 4;  // bytemap

  hist_kernel<<<NB, 256, 0, stream>>>(src, dst, pin, pout, rank,
                                      (float*)d_out, (unsigned*)mmap, E, chunk);
  merge_kernel<<<(NW4 + 31) / 32, 256, 0, stream>>>(pin, pout, in_cnt, ns, nd,
                                                    mask, mmap, NM);

  int prep_blocks = 512 + (N * 32 + 255) / 256;
  fillprep_kernel<<<prep_blocks, 256, 0, stream>>>(
      src, dst, rank, pin, csr, attr, Ws, decW, ns, token, mmap,
      X, Wt, E, chunk, N * 32);

  // layers 0,1: full graph (their outputs feed the next aggregation)
  for (int l = 0; l < 2; ++l) {
    agg_kernel<<<(N + 3) / 4, 256, 0, stream>>>(
        (const unsigned short*)X, csr, in_cnt, nd, nullptr,
        (unsigned short*)Y, N);
    gemm_layer_kernel<<<(N + 63) / 64, 256, 0, stream>>>(
        Y, Wt + (size_t)l * HID * HID, X, bs + (size_t)l * HID, ns, N);
  }

  // layer 2: only masked nodes are consumed downstream -> compact 15000 rows
  agg_kernel<<<(NM + 3) / 4, 256, 0, stream>>>(
      (const unsigned short*)X, csr, in_cnt, nd, mask,
      (unsigned short*)Y, NM);
  gemm_layer_kernel<<<(NM + 63) / 64, 256, 0, stream>>>(
      Y, Wt + (size_t)2 * HID * HID, X, bs + (size_t)2 * HID, nullptr, NM);

  // loss = mean((X_compact @ decW + decb - attr[mask])^2)
  gemm_loss_kernel<<<(NM + 63) / 64, 256, 0, stream>>>(
      X, Wt + (size_t)3 * HID * HID, decb, mask, attr, (float*)d_out,
      NM, 1.f / ((float)NM * HID));
}